// Round 19
// baseline (43.946 us; speedup 1.0000x reference)
//
#include <hip/hip_runtime.h>
#include <cmath>

#define D_ 128
#define B_ 256
#define P_ 64
#define R_ 32
#define GROWS 192        /* rel rows per batch block */
#define EPS_ 1e-8f

typedef unsigned short u16;
typedef unsigned int   u32;
using bf16x8 = __attribute__((ext_vector_type(8))) __bf16;
using f32x4  = __attribute__((ext_vector_type(4))) float;

__device__ __forceinline__ float sigm_f(float x){ return 1.0f/(1.0f + __expf(-x)); }
__device__ __forceinline__ float tanh_f(float x){
    float e = __expf(2.0f*x);
    return 1.0f - 2.0f/(e + 1.0f);
}

__device__ __forceinline__ u16 f2b(float f){         // fp32 -> bf16 RNE
    u32 u = __builtin_bit_cast(u32, f);
    u += 0x7fffu + ((u >> 16) & 1u);
    return (u16)(u >> 16);
}
__device__ __forceinline__ float b2f(u16 s){
    return __builtin_bit_cast(float, ((u32)s) << 16);
}
__device__ __forceinline__ bf16x8 pack8(float a0,float a1,float a2,float a3,
                                        float a4,float a5,float a6,float a7){
    uint4 r;
    r.x = (u32)f2b(a0) | ((u32)f2b(a1) << 16);
    r.y = (u32)f2b(a2) | ((u32)f2b(a3) << 16);
    r.z = (u32)f2b(a4) | ((u32)f2b(a5) << 16);
    r.w = (u32)f2b(a6) | ((u32)f2b(a7) << 16);
    return __builtin_bit_cast(bf16x8, r);
}
__device__ __forceinline__ bf16x8 ldg8(const u16* p){
    return __builtin_bit_cast(bf16x8, *(const uint4*)p);
}
// swizzled LDS bf16 tile: slot(row, granule g) at row*128 + ((g^(row&7))<<3)
__device__ __forceinline__ bf16x8 ldA(const u16* Xs, int row, int gk){
    return __builtin_bit_cast(bf16x8,
        *(const uint4*)(&Xs[row*128 + ((gk ^ (row & 7)) << 3)]));
}
__device__ __forceinline__ int swz_slot(int row, int col){
    return row*128 + (((col >> 3) ^ (row & 7)) << 3) + (col & 7);
}

// ---------------- K1: weight convert fp32 -> bf16 ----------------
__global__ __launch_bounds__(1024) void k_wcvt(
    const float* __restrict__ wd, const float* __restrict__ we,
    const float* __restrict__ wp, const float* __restrict__ wih,
    const float* __restrict__ whh,
    u16* __restrict__ wdb, u16* __restrict__ web, u16* __restrict__ wpb,
    u16* __restrict__ wib, u16* __restrict__ whb)
{
    int i = blockIdx.x*1024 + threadIdx.x;    // 0..18431
    int e = i*8;
    const float* src; u16* dst; int off;
    if      (e < 16384) { src = wd;  dst = wdb; off = e; }
    else if (e < 32768) { src = we;  dst = web; off = e - 16384; }
    else if (e < 49152) { src = wp;  dst = wpb; off = e - 32768; }
    else if (e < 98304) { src = wih; dst = wib; off = e - 49152; }
    else                { src = whh; dst = whb; off = e - 98304; }
    float4 a = *(const float4*)(src + off);
    float4 b = *(const float4*)(src + off + 4);
    uint4 r;
    r.x = (u32)f2b(a.x) | ((u32)f2b(a.y) << 16);
    r.y = (u32)f2b(a.z) | ((u32)f2b(a.w) << 16);
    r.z = (u32)f2b(b.x) | ((u32)f2b(b.y) << 16);
    r.w = (u32)f2b(b.z) | ((u32)f2b(b.w) << 16);
    *(uint4*)(dst + off) = r;
}

// ---------------- K2: per-batch mega kernel (burst gather + issue-early) ----------------
// grid 256, 512 thr (8 waves x 16-col strips)
__global__ __launch_bounds__(512,2) void k_mega(
    const int* __restrict__ pair, const int* __restrict__ relset,
    const int* __restrict__ path,
    const float* __restrict__ emb, const float* __restrict__ eu,
    const float* __restrict__ eub,
    const u16* __restrict__ wdb, const float* __restrict__ bd,
    const u16* __restrict__ web, const float* __restrict__ be,
    const u16* __restrict__ wpb, const float* __restrict__ bpv_,
    const u16* __restrict__ wib, const u16* __restrict__ whb,
    const float* __restrict__ bih, const float* __restrict__ bhh,
    float* __restrict__ out)
{
    __shared__ u16   Xs[GROWS*128];          // 48 KB rel tile (swizzled bf16)
    __shared__ u16   X2[GROWS*128];          // 48 KB cost-adjusted tile
    __shared__ u16   Hs[64*128];             // 16 KB GRU state
    __shared__ float pdh[GROWS], pdt[GROWS], pdu[GROWS], pnn[GROWS];
    __shared__ float sdS[GROWS], seS[GROWS];
    __shared__ float s_hts, s_hi, s_ti;
    __shared__ float s_part[8];

    const int b    = blockIdx.x;
    const int tid  = threadIdx.x;
    const int wave = tid >> 6, lane = tid & 63;
    const int lrow = lane & 15, lk8 = lane >> 4;
    const int col  = wave*16 + lrow;
    const float eb = eub[0];
    const int ph = pair[2*b], ptl = pair[2*b+1];

    // ---- P1: burst-issue ALL gather loads, then stats/denominator, then drain ----
    {
        const int l16 = tid & 15;
        const int grp = tid >> 4;            // 0..31  16-lane group id
        int pidx[6];
        #pragma unroll
        for (int i = 0; i < 6; ++i) pidx[i] = path[b*GROWS + i*32 + grp];
        float4 rv0[6], rv1[6];
        #pragma unroll
        for (int i = 0; i < 6; ++i) {
            const float* sp = emb + (size_t)pidx[i]*128 + l16*8;
            rv0[i] = *(const float4*)sp;
            rv1[i] = *(const float4*)(sp + 4);
        }
        float hq[8], tq[8], uq[8];
        {
            const float* hpq = emb + (size_t)ph*128  + l16*8;
            const float* tpq = emb + (size_t)ptl*128 + l16*8;
            const float* upq = eu + l16*8;
            float4 a0 = *(const float4*)hpq, a1 = *(const float4*)(hpq+4);
            float4 b0 = *(const float4*)tpq, b1 = *(const float4*)(tpq+4);
            float4 c0 = *(const float4*)upq, c1 = *(const float4*)(upq+4);
            hq[0]=a0.x;hq[1]=a0.y;hq[2]=a0.z;hq[3]=a0.w;hq[4]=a1.x;hq[5]=a1.y;hq[6]=a1.z;hq[7]=a1.w;
            tq[0]=b0.x;tq[1]=b0.y;tq[2]=b0.z;tq[3]=b0.w;tq[4]=b1.x;tq[5]=b1.y;tq[6]=b1.z;tq[7]=b1.w;
            uq[0]=c0.x;uq[1]=c0.y;uq[2]=c0.z;uq[3]=c0.w;uq[4]=c1.x;uq[5]=c1.y;uq[6]=c1.z;uq[7]=c1.w;
        }
        if (wave == 0) {
            float2 hv2 = *(const float2*)(emb + (size_t)ph*128 + 2*lane);
            float2 tv2 = *(const float2*)(emb + (size_t)ptl*128 + 2*lane);
            float dht = hv2.x*tv2.x + hv2.y*tv2.y;
            float dhh = hv2.x*hv2.x + hv2.y*hv2.y;
            float dtt = tv2.x*tv2.x + tv2.y*tv2.y;
            #pragma unroll
            for (int o = 32; o > 0; o >>= 1) {
                dht += __shfl_xor(dht, o);
                dhh += __shfl_xor(dhh, o);
                dtt += __shfl_xor(dtt, o);
            }
            if (lane == 0) {
                float hn = 1.f / fmaxf(sqrtf(dhh), EPS_);
                float tn = 1.f / fmaxf(sqrtf(dtt), EPS_);
                s_hts = dht*hn*tn;
                s_hi  = hn;
                s_ti  = tn;
            }
        }
        {
            float2 uv2 = *(const float2*)(eu + 2*lane);
            int ri[4];
            #pragma unroll
            for (int k = 0; k < 4; ++k) ri[k] = relset[b*R_ + wave*4 + k];
            float2 ev[4];
            #pragma unroll
            for (int k = 0; k < 4; ++k)
                ev[k] = *(const float2*)(emb + (size_t)ri[k]*128 + 2*lane);
            float accs = 0.f;
            #pragma unroll
            for (int k = 0; k < 4; ++k) {
                float du = ev[k].x*uv2.x + ev[k].y*uv2.y;
                #pragma unroll
                for (int o = 32; o > 0; o >>= 1) du += __shfl_xor(du, o);
                accs += __expf(du + eb);
            }
            if (lane == 0) s_part[wave] = accs;
        }
        #pragma unroll
        for (int i = 0; i < 6; ++i) {
            const int r = i*32 + grp;
            float v[8] = {rv0[i].x,rv0[i].y,rv0[i].z,rv0[i].w,
                          rv1[i].x,rv1[i].y,rv1[i].z,rv1[i].w};
            float dh=0.f, dt=0.f, du=0.f, nn=0.f;
            #pragma unroll
            for (int j = 0; j < 8; ++j) {
                dh = fmaf(v[j], hq[j], dh);
                dt = fmaf(v[j], tq[j], dt);
                du = fmaf(v[j], uq[j], du);
                nn = fmaf(v[j], v[j], nn);
            }
            #pragma unroll
            for (int o = 8; o > 0; o >>= 1) {
                dh += __shfl_xor(dh, o);
                dt += __shfl_xor(dt, o);
                du += __shfl_xor(du, o);
                nn += __shfl_xor(nn, o);
            }
            if (l16 == 0) { pdh[r]=dh; pdt[r]=dt; pdu[r]=du; pnn[r]=nn; }
            bf16x8 bv = pack8(v[0],v[1],v[2],v[3],v[4],v[5],v[6],v[7]);
            *(uint4*)(&Xs[r*128 + ((l16 ^ (r & 7)) << 3)]) = __builtin_bit_cast(uint4, bv);
        }
    }

    // ---- issue-early: D/E fragments AND P fragments (ride through 2 barriers) ----
    bf16x8 fD[4], fE[4], fP[4];
    #pragma unroll
    for (int ks = 0; ks < 4; ++ks) {
        const int gk = ks*4 + lk8;
        fD[ks] = ldg8(wdb + col*128 + gk*8);
        fE[ks] = ldg8(web + col*128 + gk*8);
        fP[ks] = ldg8(wpb + col*128 + gk*8);
    }
    __syncthreads();

    // ---- P3: sd/se scalars (thread p = tid < 64) ----
    if (tid < 64) {
        float is = 0.f;
        #pragma unroll
        for (int w = 0; w < 8; ++w) is += s_part[w];
        is = 1.f/is;
        const float hi = s_hi, ti = s_ti, ht = s_hts;
        const int r1 = 3*tid, r2 = r1+1, r3 = r1+2;
        float n1i = 1.f / fmaxf(sqrtf(pnn[r1]), EPS_);
        float n2i = 1.f / fmaxf(sqrtf(pnn[r2]), EPS_);
        float se1 = 0.5f*(pdh[r1]*hi + pdt[r1]*ti)*n1i;
        float se2 = 0.5f*(pdh[r2]*hi + pdt[r2]*ti)*n2i;
        sdS[r1] = (1.f - 0.5f*(ht  + se1))*0.5f;
        sdS[r2] = (1.f - 0.5f*(se1 + se2))*0.5f;
        sdS[r3] = (1.f - 0.5f*(ht  + se2))*0.5f;
        seS[r1] = __expf(pdu[r1] + eb)*is;
        seS[r2] = __expf(pdu[r2] + eb)*is;
        seS[r3] = __expf(pdu[r3] + eb)*is;
    }
    __syncthreads();

    // ---- P4a: STREAMING D/E GEMM + cost epilogue -> X2 ----
    {
        const float bde = bd[col] + be[col];
        __builtin_amdgcn_s_setprio(1);
        #pragma unroll 2
        for (int mt = 0; mt < 12; ++mt) {
            f32x4 aD = (f32x4){0,0,0,0}, aE = (f32x4){0,0,0,0};
            #pragma unroll
            for (int ks = 0; ks < 4; ++ks) {
                const int gk = ks*4 + lk8;
                bf16x8 a = ldA(Xs, mt*16 + lrow, gk);
                aD = __builtin_amdgcn_mfma_f32_16x16x32_bf16(a, fD[ks], aD, 0,0,0);
                aE = __builtin_amdgcn_mfma_f32_16x16x32_bf16(a, fE[ks], aE, 0,0,0);
            }
            #pragma unroll
            for (int rr = 0; rr < 4; ++rr) {
                const int row = mt*16 + lk8*4 + rr;
                const int sl  = swz_slot(row, col);
                float relv = b2f(Xs[sl]);
                float c = sdS[row]*aD[rr] + seS[row]*aE[rr] + bde;
                X2[sl] = f2b(relv - 1e-3f*fmaxf(c, 0.f));
            }
        }
        __builtin_amdgcn_s_setprio(0);
    }

    // ---- issue-early: GRU x-side weight fragments (hide under barrier + P4b) ----
    bf16x8 wR[4], wZ[4], wI[4];
    #pragma unroll
    for (int ks = 0; ks < 4; ++ks) {
        const int gk = ks*4 + lk8;
        wR[ks] = ldg8(wib +           col*128 + gk*8);
        wZ[ks] = ldg8(wib + 16384   + col*128 + gk*8);
        wI[ks] = ldg8(wib + 2*16384 + col*128 + gk*8);
    }
    __syncthreads();   // X2 complete

    // ---- P4b: STREAMING P GEMM -> rel_in back into Xs ----
    {
        const float bpv = bpv_[col];
        __builtin_amdgcn_s_setprio(1);
        #pragma unroll 2
        for (int mt = 0; mt < 12; ++mt) {
            f32x4 aP = (f32x4){0,0,0,0};
            #pragma unroll
            for (int ks = 0; ks < 4; ++ks) {
                const int gk = ks*4 + lk8;
                bf16x8 a = ldA(X2, mt*16 + lrow, gk);
                aP = __builtin_amdgcn_mfma_f32_16x16x32_bf16(a, fP[ks], aP, 0,0,0);
            }
            #pragma unroll
            for (int rr = 0; rr < 4; ++rr) {
                const int row = mt*16 + lk8*4 + rr;
                Xs[swz_slot(row, col)] = f2b(aP[rr] + bpv);
            }
        }
        __builtin_amdgcn_s_setprio(0);
    }

    const float brv = bih[col]       + bhh[col];
    const float bzv = bih[128 + col] + bhh[128 + col];
    const float biN = bih[256 + col];
    const float bhN = bhh[256 + col];
    __syncthreads();   // Xs = rel_in complete

    // ---- P5: GRU over 64 bp rows; h-side weights reloaded per t (L2-hot bf16) ----
    float hreg[4][4];
    f32x4 aR[4], aZ[4], aI[4], aH[4];

    // t = 0 (h = 0)
    #pragma unroll
    for (int m = 0; m < 4; ++m) { aR[m]=(f32x4){0,0,0,0}; aZ[m]=(f32x4){0,0,0,0}; aI[m]=(f32x4){0,0,0,0}; }
    __builtin_amdgcn_s_setprio(1);
    #pragma unroll
    for (int ks = 0; ks < 4; ++ks) {
        const int gk = ks*4 + lk8;
        #pragma unroll
        for (int mt = 0; mt < 4; ++mt) {
            bf16x8 ax = ldA(Xs, 3*(mt*16 + lrow) + 0, gk);
            aR[mt] = __builtin_amdgcn_mfma_f32_16x16x32_bf16(ax, wR[ks], aR[mt], 0,0,0);
            aZ[mt] = __builtin_amdgcn_mfma_f32_16x16x32_bf16(ax, wZ[ks], aZ[mt], 0,0,0);
            aI[mt] = __builtin_amdgcn_mfma_f32_16x16x32_bf16(ax, wI[ks], aI[mt], 0,0,0);
        }
    }
    __builtin_amdgcn_s_setprio(0);
    #pragma unroll
    for (int mt = 0; mt < 4; ++mt)
        #pragma unroll
        for (int rr = 0; rr < 4; ++rr) {
            const int row = mt*16 + lk8*4 + rr;
            float rv = sigm_f(aR[mt][rr] + brv);
            float zv = sigm_f(aZ[mt][rr] + bzv);
            float nn = tanh_f(aI[mt][rr] + biN + rv*bhN);
            float h2 = (1.f - zv)*nn;
            hreg[mt][rr] = h2;
            Hs[swz_slot(row, col)] = f2b(h2);
        }
    __syncthreads();

    // t = 1, 2
    #pragma unroll
    for (int t = 1; t < 3; ++t) {
        #pragma unroll
        for (int m = 0; m < 4; ++m) { aR[m]=(f32x4){0,0,0,0}; aZ[m]=(f32x4){0,0,0,0}; aI[m]=(f32x4){0,0,0,0}; aH[m]=(f32x4){0,0,0,0}; }
        __builtin_amdgcn_s_setprio(1);
        #pragma unroll
        for (int ks = 0; ks < 4; ++ks) {
            const int gk = ks*4 + lk8;
            bf16x8 vRk = ldg8(whb +           col*128 + gk*8);
            bf16x8 vZk = ldg8(whb + 16384   + col*128 + gk*8);
            bf16x8 vHk = ldg8(whb + 2*16384 + col*128 + gk*8);
            #pragma unroll
            for (int mt = 0; mt < 4; ++mt) {
                bf16x8 ax = ldA(Xs, 3*(mt*16 + lrow) + t, gk);
                bf16x8 ah = ldA(Hs, mt*16 + lrow, gk);
                aR[mt] = __builtin_amdgcn_mfma_f32_16x16x32_bf16(ax, wR[ks], aR[mt], 0,0,0);
                aZ[mt] = __builtin_amdgcn_mfma_f32_16x16x32_bf16(ax, wZ[ks], aZ[mt], 0,0,0);
                aI[mt] = __builtin_amdgcn_mfma_f32_16x16x32_bf16(ax, wI[ks], aI[mt], 0,0,0);
                aR[mt] = __builtin_amdgcn_mfma_f32_16x16x32_bf16(ah, vRk, aR[mt], 0,0,0);
                aZ[mt] = __builtin_amdgcn_mfma_f32_16x16x32_bf16(ah, vZk, aZ[mt], 0,0,0);
                aH[mt] = __builtin_amdgcn_mfma_f32_16x16x32_bf16(ah, vHk, aH[mt], 0,0,0);
            }
        }
        __builtin_amdgcn_s_setprio(0);
        __syncthreads();              // all Hs reads of this step complete
        if (t < 2) {
            #pragma unroll
            for (int mt = 0; mt < 4; ++mt)
                #pragma unroll
                for (int rr = 0; rr < 4; ++rr) {
                    const int row = mt*16 + lk8*4 + rr;
                    float rv = sigm_f(aR[mt][rr] + brv);
                    float zv = sigm_f(aZ[mt][rr] + bzv);
                    float hn = aH[mt][rr] + bhN;
                    float nn = tanh_f(aI[mt][rr] + biN + rv*hn);
                    float h2 = (1.f - zv)*nn + zv*hreg[mt][rr];
                    hreg[mt][rr] = h2;
                    Hs[swz_slot(row, col)] = f2b(h2);
                }
            __syncthreads();
        } else {
            const int bp0 = b*64;
            #pragma unroll
            for (int mt = 0; mt < 4; ++mt)
                #pragma unroll
                for (int rr = 0; rr < 4; ++rr) {
                    const int row = mt*16 + lk8*4 + rr;
                    float rv = sigm_f(aR[mt][rr] + brv);
                    float zv = sigm_f(aZ[mt][rr] + bzv);
                    float hn = aH[mt][rr] + bhN;
                    float nn = tanh_f(aI[mt][rr] + biN + rv*hn);
                    float h2 = (1.f - zv)*nn + zv*hreg[mt][rr];
                    out[(size_t)(bp0 + row)*128 + col] = h2;
                }
        }
    }
}

extern "C" void kernel_launch(void* const* d_in, const int* in_sizes, int n_in,
                              void* d_out, int out_size, void* d_ws, size_t ws_size,
                              hipStream_t stream)
{
    const int*   path   = (const int*)d_in[0];
    const int*   pair   = (const int*)d_in[1];
    const int*   relset = (const int*)d_in[2];
    const float* emb    = (const float*)d_in[3];
    const float* wd     = (const float*)d_in[4];
    const float* bd     = (const float*)d_in[5];
    const float* we     = (const float*)d_in[6];
    const float* be     = (const float*)d_in[7];
    const float* wp     = (const float*)d_in[8];
    const float* bp     = (const float*)d_in[9];
    const float* eu     = (const float*)d_in[10];
    const float* eub    = (const float*)d_in[11];
    const float* wih    = (const float*)d_in[12];
    const float* whh    = (const float*)d_in[13];
    const float* bih    = (const float*)d_in[14];
    const float* bhh    = (const float*)d_in[15];
    float* out = (float*)d_out;
    float* ws  = (float*)d_ws;

    // workspace: only bf16 weights (~288 KB)
    u16* wdb = (u16*)ws;               // 16384 u16
    u16* web = wdb + 16384;
    u16* wpb = web + 16384;
    u16* wib = wpb + 16384;            // 49152 u16
    u16* whb = wib + 49152;            // ends at 147456 u16 = 288 KB

    k_wcvt<<<18, 1024, 0, stream>>>(wd, we, wp, wih, whh, wdb, web, wpb, wib, whb);
    k_mega<<<B_, 512, 0, stream>>>(pair, relset, path, emb, eu, eub,
                                   wdb, bd, web, be, wpb, bp,
                                   wib, whb, bih, bhh, out);
}

// Round 20
// 42.173 us; speedup vs baseline: 1.0420x; 1.0420x over previous
//
#include <hip/hip_runtime.h>
#include <cmath>

#define D_ 128
#define B_ 256
#define P_ 64
#define R_ 32
#define GROWS 192        /* rel rows per batch block */
#define EPS_ 1e-8f

typedef unsigned short u16;
typedef unsigned int   u32;
using bf16x8 = __attribute__((ext_vector_type(8))) __bf16;
using f32x4  = __attribute__((ext_vector_type(4))) float;

__device__ __forceinline__ float sigm_f(float x){ return 1.0f/(1.0f + __expf(-x)); }
__device__ __forceinline__ float tanh_f(float x){
    float e = __expf(2.0f*x);
    return 1.0f - 2.0f/(e + 1.0f);
}

__device__ __forceinline__ u16 f2b(float f){         // fp32 -> bf16 RNE
    u32 u = __builtin_bit_cast(u32, f);
    u += 0x7fffu + ((u >> 16) & 1u);
    return (u16)(u >> 16);
}
__device__ __forceinline__ float b2f(u16 s){
    return __builtin_bit_cast(float, ((u32)s) << 16);
}
__device__ __forceinline__ bf16x8 pack8(float a0,float a1,float a2,float a3,
                                        float a4,float a5,float a6,float a7){
    uint4 r;
    r.x = (u32)f2b(a0) | ((u32)f2b(a1) << 16);
    r.y = (u32)f2b(a2) | ((u32)f2b(a3) << 16);
    r.z = (u32)f2b(a4) | ((u32)f2b(a5) << 16);
    r.w = (u32)f2b(a6) | ((u32)f2b(a7) << 16);
    return __builtin_bit_cast(bf16x8, r);
}
__device__ __forceinline__ bf16x8 ldg8(const u16* p){
    return __builtin_bit_cast(bf16x8, *(const uint4*)p);
}
// swizzled LDS bf16 tile: slot(row, granule g) at row*128 + ((g^(row&7))<<3)
__device__ __forceinline__ bf16x8 ldA(const u16* Xs, int row, int gk){
    return __builtin_bit_cast(bf16x8,
        *(const uint4*)(&Xs[row*128 + ((gk ^ (row & 7)) << 3)]));
}
__device__ __forceinline__ int swz_slot(int row, int col){
    return row*128 + (((col >> 3) ^ (row & 7)) << 3) + (col & 7);
}

// ---------------- K1: weight convert fp32 -> bf16 ----------------
__global__ __launch_bounds__(1024) void k_wcvt(
    const float* __restrict__ wd, const float* __restrict__ we,
    const float* __restrict__ wp, const float* __restrict__ wih,
    const float* __restrict__ whh,
    u16* __restrict__ wdb, u16* __restrict__ web, u16* __restrict__ wpb,
    u16* __restrict__ wib, u16* __restrict__ whb)
{
    int i = blockIdx.x*1024 + threadIdx.x;    // 0..18431
    int e = i*8;
    const float* src; u16* dst; int off;
    if      (e < 16384) { src = wd;  dst = wdb; off = e; }
    else if (e < 32768) { src = we;  dst = web; off = e - 16384; }
    else if (e < 49152) { src = wp;  dst = wpb; off = e - 32768; }
    else if (e < 98304) { src = wih; dst = wib; off = e - 49152; }
    else                { src = whh; dst = whb; off = e - 98304; }
    float4 a = *(const float4*)(src + off);
    float4 b = *(const float4*)(src + off + 4);
    uint4 r;
    r.x = (u32)f2b(a.x) | ((u32)f2b(a.y) << 16);
    r.y = (u32)f2b(a.z) | ((u32)f2b(a.w) << 16);
    r.z = (u32)f2b(b.x) | ((u32)f2b(b.y) << 16);
    r.w = (u32)f2b(b.z) | ((u32)f2b(b.w) << 16);
    *(uint4*)(dst + off) = r;
}

// ---------------- K2: per-batch mega kernel (burst gather + dbuf-H GRU) ----------------
// grid 256, 512 thr (8 waves x 16-col strips)
__global__ __launch_bounds__(512,2) void k_mega(
    const int* __restrict__ pair, const int* __restrict__ relset,
    const int* __restrict__ path,
    const float* __restrict__ emb, const float* __restrict__ eu,
    const float* __restrict__ eub,
    const u16* __restrict__ wdb, const float* __restrict__ bd,
    const u16* __restrict__ web, const float* __restrict__ be,
    const u16* __restrict__ wpb, const float* __restrict__ bpv_,
    const u16* __restrict__ wib, const u16* __restrict__ whb,
    const float* __restrict__ bih, const float* __restrict__ bhh,
    float* __restrict__ out)
{
    __shared__ u16   Xs[GROWS*128];          // 48 KB rel tile (swizzled bf16)
    __shared__ u16   X2[GROWS*128];          // 48 KB cost tile; first 16 KB reused as H0
    __shared__ u16   Hs[64*128];             // 16 KB GRU state (H1)
    __shared__ float pdh[GROWS], pdt[GROWS], pdu[GROWS], pnn[GROWS];
    __shared__ float sdS[GROWS], seS[GROWS];
    __shared__ float s_hts, s_hi, s_ti;
    __shared__ float s_part[8];

    const int b    = blockIdx.x;
    const int tid  = threadIdx.x;
    const int wave = tid >> 6, lane = tid & 63;
    const int lrow = lane & 15, lk8 = lane >> 4;
    const int col  = wave*16 + lrow;
    const float eb = eub[0];
    const int ph = pair[2*b], ptl = pair[2*b+1];

    // ---- P1: burst-issue ALL gather loads, then stats/denominator, then drain ----
    {
        const int l16 = tid & 15;
        const int grp = tid >> 4;            // 0..31  16-lane group id
        int pidx[6];
        #pragma unroll
        for (int i = 0; i < 6; ++i) pidx[i] = path[b*GROWS + i*32 + grp];
        float4 rv0[6], rv1[6];
        #pragma unroll
        for (int i = 0; i < 6; ++i) {
            const float* sp = emb + (size_t)pidx[i]*128 + l16*8;
            rv0[i] = *(const float4*)sp;
            rv1[i] = *(const float4*)(sp + 4);
        }
        float hq[8], tq[8], uq[8];
        {
            const float* hpq = emb + (size_t)ph*128  + l16*8;
            const float* tpq = emb + (size_t)ptl*128 + l16*8;
            const float* upq = eu + l16*8;
            float4 a0 = *(const float4*)hpq, a1 = *(const float4*)(hpq+4);
            float4 b0 = *(const float4*)tpq, b1 = *(const float4*)(tpq+4);
            float4 c0 = *(const float4*)upq, c1 = *(const float4*)(upq+4);
            hq[0]=a0.x;hq[1]=a0.y;hq[2]=a0.z;hq[3]=a0.w;hq[4]=a1.x;hq[5]=a1.y;hq[6]=a1.z;hq[7]=a1.w;
            tq[0]=b0.x;tq[1]=b0.y;tq[2]=b0.z;tq[3]=b0.w;tq[4]=b1.x;tq[5]=b1.y;tq[6]=b1.z;tq[7]=b1.w;
            uq[0]=c0.x;uq[1]=c0.y;uq[2]=c0.z;uq[3]=c0.w;uq[4]=c1.x;uq[5]=c1.y;uq[6]=c1.z;uq[7]=c1.w;
        }
        if (wave == 0) {
            float2 hv2 = *(const float2*)(emb + (size_t)ph*128 + 2*lane);
            float2 tv2 = *(const float2*)(emb + (size_t)ptl*128 + 2*lane);
            float dht = hv2.x*tv2.x + hv2.y*tv2.y;
            float dhh = hv2.x*hv2.x + hv2.y*hv2.y;
            float dtt = tv2.x*tv2.x + tv2.y*tv2.y;
            #pragma unroll
            for (int o = 32; o > 0; o >>= 1) {
                dht += __shfl_xor(dht, o);
                dhh += __shfl_xor(dhh, o);
                dtt += __shfl_xor(dtt, o);
            }
            if (lane == 0) {
                float hn = 1.f / fmaxf(sqrtf(dhh), EPS_);
                float tn = 1.f / fmaxf(sqrtf(dtt), EPS_);
                s_hts = dht*hn*tn;
                s_hi  = hn;
                s_ti  = tn;
            }
        }
        {
            float2 uv2 = *(const float2*)(eu + 2*lane);
            int ri[4];
            #pragma unroll
            for (int k = 0; k < 4; ++k) ri[k] = relset[b*R_ + wave*4 + k];
            float2 ev[4];
            #pragma unroll
            for (int k = 0; k < 4; ++k)
                ev[k] = *(const float2*)(emb + (size_t)ri[k]*128 + 2*lane);
            float accs = 0.f;
            #pragma unroll
            for (int k = 0; k < 4; ++k) {
                float du = ev[k].x*uv2.x + ev[k].y*uv2.y;
                #pragma unroll
                for (int o = 32; o > 0; o >>= 1) du += __shfl_xor(du, o);
                accs += __expf(du + eb);
            }
            if (lane == 0) s_part[wave] = accs;
        }
        #pragma unroll
        for (int i = 0; i < 6; ++i) {
            const int r = i*32 + grp;
            float v[8] = {rv0[i].x,rv0[i].y,rv0[i].z,rv0[i].w,
                          rv1[i].x,rv1[i].y,rv1[i].z,rv1[i].w};
            float dh=0.f, dt=0.f, du=0.f, nn=0.f;
            #pragma unroll
            for (int j = 0; j < 8; ++j) {
                dh = fmaf(v[j], hq[j], dh);
                dt = fmaf(v[j], tq[j], dt);
                du = fmaf(v[j], uq[j], du);
                nn = fmaf(v[j], v[j], nn);
            }
            #pragma unroll
            for (int o = 8; o > 0; o >>= 1) {
                dh += __shfl_xor(dh, o);
                dt += __shfl_xor(dt, o);
                du += __shfl_xor(du, o);
                nn += __shfl_xor(nn, o);
            }
            if (l16 == 0) { pdh[r]=dh; pdt[r]=dt; pdu[r]=du; pnn[r]=nn; }
            bf16x8 bv = pack8(v[0],v[1],v[2],v[3],v[4],v[5],v[6],v[7]);
            *(uint4*)(&Xs[r*128 + ((l16 ^ (r & 7)) << 3)]) = __builtin_bit_cast(uint4, bv);
        }
    }

    // ---- D/E weight fragments (bf16, pre-converted) — after the burst ----
    bf16x8 fD[4], fE[4];
    #pragma unroll
    for (int ks = 0; ks < 4; ++ks) {
        const int gk = ks*4 + lk8;
        fD[ks] = ldg8(wdb + col*128 + gk*8);
        fE[ks] = ldg8(web + col*128 + gk*8);
    }
    __syncthreads();

    // ---- P3: sd/se scalars (thread p = tid < 64) ----
    if (tid < 64) {
        float is = 0.f;
        #pragma unroll
        for (int w = 0; w < 8; ++w) is += s_part[w];
        is = 1.f/is;
        const float hi = s_hi, ti = s_ti, ht = s_hts;
        const int r1 = 3*tid, r2 = r1+1, r3 = r1+2;
        float n1i = 1.f / fmaxf(sqrtf(pnn[r1]), EPS_);
        float n2i = 1.f / fmaxf(sqrtf(pnn[r2]), EPS_);
        float se1 = 0.5f*(pdh[r1]*hi + pdt[r1]*ti)*n1i;
        float se2 = 0.5f*(pdh[r2]*hi + pdt[r2]*ti)*n2i;
        sdS[r1] = (1.f - 0.5f*(ht  + se1))*0.5f;
        sdS[r2] = (1.f - 0.5f*(se1 + se2))*0.5f;
        sdS[r3] = (1.f - 0.5f*(ht  + se2))*0.5f;
        seS[r1] = __expf(pdu[r1] + eb)*is;
        seS[r2] = __expf(pdu[r2] + eb)*is;
        seS[r3] = __expf(pdu[r3] + eb)*is;
    }
    __syncthreads();

    // ---- P4a: STREAMING D/E GEMM + cost epilogue -> X2 (no mid barriers) ----
    {
        const float bde = bd[col] + be[col];
        #pragma unroll 2
        for (int mt = 0; mt < 12; ++mt) {
            f32x4 aD = (f32x4){0,0,0,0}, aE = (f32x4){0,0,0,0};
            #pragma unroll
            for (int ks = 0; ks < 4; ++ks) {
                const int gk = ks*4 + lk8;
                bf16x8 a = ldA(Xs, mt*16 + lrow, gk);
                aD = __builtin_amdgcn_mfma_f32_16x16x32_bf16(a, fD[ks], aD, 0,0,0);
                aE = __builtin_amdgcn_mfma_f32_16x16x32_bf16(a, fE[ks], aE, 0,0,0);
            }
            #pragma unroll
            for (int rr = 0; rr < 4; ++rr) {
                const int row = mt*16 + lk8*4 + rr;
                const int sl  = swz_slot(row, col);
                float relv = b2f(Xs[sl]);
                float c = sdS[row]*aD[rr] + seS[row]*aE[rr] + bde;
                X2[sl] = f2b(relv - 1e-3f*fmaxf(c, 0.f));
            }
        }
    }
    __syncthreads();   // X2 complete

    // ---- P4b: STREAMING P GEMM -> rel_in back into Xs ----
    {
        bf16x8 fP[4];
        #pragma unroll
        for (int ks = 0; ks < 4; ++ks)
            fP[ks] = ldg8(wpb + col*128 + (ks*4 + lk8)*8);
        const float bpv = bpv_[col];
        #pragma unroll 2
        for (int mt = 0; mt < 12; ++mt) {
            f32x4 aP = (f32x4){0,0,0,0};
            #pragma unroll
            for (int ks = 0; ks < 4; ++ks) {
                const int gk = ks*4 + lk8;
                bf16x8 a = ldA(X2, mt*16 + lrow, gk);
                aP = __builtin_amdgcn_mfma_f32_16x16x32_bf16(a, fP[ks], aP, 0,0,0);
            }
            #pragma unroll
            for (int rr = 0; rr < 4; ++rr) {
                const int row = mt*16 + lk8*4 + rr;
                Xs[swz_slot(row, col)] = f2b(aP[rr] + bpv);
            }
        }
    }

    // ---- GRU x-side weight fragments: issue before barrier (latency hidden) ----
    bf16x8 wR[4], wZ[4], wI[4];
    #pragma unroll
    for (int ks = 0; ks < 4; ++ks) {
        const int gk = ks*4 + lk8;
        wR[ks] = ldg8(wib +           col*128 + gk*8);
        wZ[ks] = ldg8(wib + 16384   + col*128 + gk*8);
        wI[ks] = ldg8(wib + 2*16384 + col*128 + gk*8);
    }
    const float brv = bih[col]       + bhh[col];
    const float bzv = bih[128 + col] + bhh[128 + col];
    const float biN = bih[256 + col];
    const float bhN = bhh[256 + col];
    __syncthreads();   // Xs = rel_in complete; X2 reads done -> its space reusable (H0)

    // ---- P5: GRU over 64 bp rows; double-buffered H (H0 = X2 space, H1 = Hs) ----
    u16* H0 = X2;      // first 64*128 u16 of X2 reused as t0 state
    float hreg[4][4];
    f32x4 aR[4], aZ[4], aI[4], aH[4];

    // t = 0 (h = 0) -> write H0
    #pragma unroll
    for (int m = 0; m < 4; ++m) { aR[m]=(f32x4){0,0,0,0}; aZ[m]=(f32x4){0,0,0,0}; aI[m]=(f32x4){0,0,0,0}; }
    #pragma unroll
    for (int ks = 0; ks < 4; ++ks) {
        const int gk = ks*4 + lk8;
        #pragma unroll
        for (int mt = 0; mt < 4; ++mt) {
            bf16x8 ax = ldA(Xs, 3*(mt*16 + lrow) + 0, gk);
            aR[mt] = __builtin_amdgcn_mfma_f32_16x16x32_bf16(ax, wR[ks], aR[mt], 0,0,0);
            aZ[mt] = __builtin_amdgcn_mfma_f32_16x16x32_bf16(ax, wZ[ks], aZ[mt], 0,0,0);
            aI[mt] = __builtin_amdgcn_mfma_f32_16x16x32_bf16(ax, wI[ks], aI[mt], 0,0,0);
        }
    }
    #pragma unroll
    for (int mt = 0; mt < 4; ++mt)
        #pragma unroll
        for (int rr = 0; rr < 4; ++rr) {
            const int row = mt*16 + lk8*4 + rr;
            float rv = sigm_f(aR[mt][rr] + brv);
            float zv = sigm_f(aZ[mt][rr] + bzv);
            float nn = tanh_f(aI[mt][rr] + biN + rv*bhN);
            float h2 = (1.f - zv)*nn;
            hreg[mt][rr] = h2;
            H0[swz_slot(row, col)] = f2b(h2);
        }
    __syncthreads();   // H0 published

    // t = 1: read H0, write H1 (disjoint buffers -> no read-drain barrier)
    #pragma unroll
    for (int m = 0; m < 4; ++m) { aR[m]=(f32x4){0,0,0,0}; aZ[m]=(f32x4){0,0,0,0}; aI[m]=(f32x4){0,0,0,0}; aH[m]=(f32x4){0,0,0,0}; }
    #pragma unroll
    for (int ks = 0; ks < 4; ++ks) {
        const int gk = ks*4 + lk8;
        bf16x8 vRk = ldg8(whb +           col*128 + gk*8);
        bf16x8 vZk = ldg8(whb + 16384   + col*128 + gk*8);
        bf16x8 vHk = ldg8(whb + 2*16384 + col*128 + gk*8);
        #pragma unroll
        for (int mt = 0; mt < 4; ++mt) {
            bf16x8 ax = ldA(Xs, 3*(mt*16 + lrow) + 1, gk);
            bf16x8 ah = ldA(H0, mt*16 + lrow, gk);
            aR[mt] = __builtin_amdgcn_mfma_f32_16x16x32_bf16(ax, wR[ks], aR[mt], 0,0,0);
            aZ[mt] = __builtin_amdgcn_mfma_f32_16x16x32_bf16(ax, wZ[ks], aZ[mt], 0,0,0);
            aI[mt] = __builtin_amdgcn_mfma_f32_16x16x32_bf16(ax, wI[ks], aI[mt], 0,0,0);
            aR[mt] = __builtin_amdgcn_mfma_f32_16x16x32_bf16(ah, vRk, aR[mt], 0,0,0);
            aZ[mt] = __builtin_amdgcn_mfma_f32_16x16x32_bf16(ah, vZk, aZ[mt], 0,0,0);
            aH[mt] = __builtin_amdgcn_mfma_f32_16x16x32_bf16(ah, vHk, aH[mt], 0,0,0);
        }
    }
    #pragma unroll
    for (int mt = 0; mt < 4; ++mt)
        #pragma unroll
        for (int rr = 0; rr < 4; ++rr) {
            const int row = mt*16 + lk8*4 + rr;
            float rv = sigm_f(aR[mt][rr] + brv);
            float zv = sigm_f(aZ[mt][rr] + bzv);
            float hn = aH[mt][rr] + bhN;
            float nn = tanh_f(aI[mt][rr] + biN + rv*hn);
            float h2 = (1.f - zv)*nn + zv*hreg[mt][rr];
            hreg[mt][rr] = h2;
            Hs[swz_slot(row, col)] = f2b(h2);
        }
    __syncthreads();   // H1 published

    // t = 2: read H1 -> out (no trailing barrier)
    #pragma unroll
    for (int m = 0; m < 4; ++m) { aR[m]=(f32x4){0,0,0,0}; aZ[m]=(f32x4){0,0,0,0}; aI[m]=(f32x4){0,0,0,0}; aH[m]=(f32x4){0,0,0,0}; }
    #pragma unroll
    for (int ks = 0; ks < 4; ++ks) {
        const int gk = ks*4 + lk8;
        bf16x8 vRk = ldg8(whb +           col*128 + gk*8);
        bf16x8 vZk = ldg8(whb + 16384   + col*128 + gk*8);
        bf16x8 vHk = ldg8(whb + 2*16384 + col*128 + gk*8);
        #pragma unroll
        for (int mt = 0; mt < 4; ++mt) {
            bf16x8 ax = ldA(Xs, 3*(mt*16 + lrow) + 2, gk);
            bf16x8 ah = ldA(Hs, mt*16 + lrow, gk);
            aR[mt] = __builtin_amdgcn_mfma_f32_16x16x32_bf16(ax, wR[ks], aR[mt], 0,0,0);
            aZ[mt] = __builtin_amdgcn_mfma_f32_16x16x32_bf16(ax, wZ[ks], aZ[mt], 0,0,0);
            aI[mt] = __builtin_amdgcn_mfma_f32_16x16x32_bf16(ax, wI[ks], aI[mt], 0,0,0);
            aR[mt] = __builtin_amdgcn_mfma_f32_16x16x32_bf16(ah, vRk, aR[mt], 0,0,0);
            aZ[mt] = __builtin_amdgcn_mfma_f32_16x16x32_bf16(ah, vZk, aZ[mt], 0,0,0);
            aH[mt] = __builtin_amdgcn_mfma_f32_16x16x32_bf16(ah, vHk, aH[mt], 0,0,0);
        }
    }
    {
        const int bp0 = b*64;
        #pragma unroll
        for (int mt = 0; mt < 4; ++mt)
            #pragma unroll
            for (int rr = 0; rr < 4; ++rr) {
                const int row = mt*16 + lk8*4 + rr;
                float rv = sigm_f(aR[mt][rr] + brv);
                float zv = sigm_f(aZ[mt][rr] + bzv);
                float hn = aH[mt][rr] + bhN;
                float nn = tanh_f(aI[mt][rr] + biN + rv*hn);
                float h2 = (1.f - zv)*nn + zv*hreg[mt][rr];
                out[(size_t)(bp0 + row)*128 + col] = h2;
            }
    }
}

extern "C" void kernel_launch(void* const* d_in, const int* in_sizes, int n_in,
                              void* d_out, int out_size, void* d_ws, size_t ws_size,
                              hipStream_t stream)
{
    const int*   path   = (const int*)d_in[0];
    const int*   pair   = (const int*)d_in[1];
    const int*   relset = (const int*)d_in[2];
    const float* emb    = (const float*)d_in[3];
    const float* wd     = (const float*)d_in[4];
    const float* bd     = (const float*)d_in[5];
    const float* we     = (const float*)d_in[6];
    const float* be     = (const float*)d_in[7];
    const float* wp     = (const float*)d_in[8];
    const float* bp     = (const float*)d_in[9];
    const float* eu     = (const float*)d_in[10];
    const float* eub    = (const float*)d_in[11];
    const float* wih    = (const float*)d_in[12];
    const float* whh    = (const float*)d_in[13];
    const float* bih    = (const float*)d_in[14];
    const float* bhh    = (const float*)d_in[15];
    float* out = (float*)d_out;
    float* ws  = (float*)d_ws;

    // workspace: only bf16 weights (~288 KB)
    u16* wdb = (u16*)ws;               // 16384 u16
    u16* web = wdb + 16384;
    u16* wpb = web + 16384;
    u16* wib = wpb + 16384;            // 49152 u16
    u16* whb = wib + 49152;            // ends at 147456 u16 = 288 KB

    k_wcvt<<<18, 1024, 0, stream>>>(wd, we, wp, wih, whh, wdb, web, wpb, wib, whb);
    k_mega<<<B_, 512, 0, stream>>>(pair, relset, path, emb, eu, eub,
                                   wdb, bd, web, be, wpb, bp,
                                   wib, whb, bih, bhh, out);
}